// Round 2
// 471.151 us; speedup vs baseline: 1.3298x; 1.3298x over previous
//
#include <hip/hip_runtime.h>
#include <math.h>

#define GG 32
#define NV (GG * GG * GG)      // 32768 voxels
#define BB 4
#define DD 128
#define VPB 32                 // voxels per k_reduce block

// Monotone order-preserving float->uint encoding.
__device__ __forceinline__ unsigned int enc_f(float f) {
    unsigned int u = __float_as_uint(f);
    return (u & 0x80000000u) ? ~u : (u | 0x80000000u);
}
__device__ __forceinline__ float dec_f(unsigned int u) {
    return __uint_as_float((u & 0x80000000u) ? (u ^ 0x80000000u) : ~u);
}
#define ENC_NEG_INF 0x007FFFFFu
#define ENC_POS_INF 0xFF800000u

__global__ void k_init_small(int* __restrict__ cnt, unsigned int* __restrict__ mm) {
    int i = blockIdx.x * blockDim.x + threadIdx.x;
    if (i < BB * NV) cnt[i] = 0;
    if (i < BB * 6) mm[i] = ((i % 6) < 3) ? ENC_POS_INF : ENC_NEG_INF;
}

// grid (64, BB), block 256. Per-thread grid-stride accumulate, wave butterfly,
// LDS cross-wave, ONE thread per block does the 6 atomics (contention fix).
__global__ void k_minmax(const float* __restrict__ xyz,
                         unsigned int* __restrict__ mm, int N) {
    int b = blockIdx.y;
    int tid = threadIdx.x;
    int gid = blockIdx.x * blockDim.x + tid;
    int stride = gridDim.x * blockDim.x;
    float mn[3] = {INFINITY, INFINITY, INFINITY};
    float mx[3] = {-INFINITY, -INFINITY, -INFINITY};
    const float* base = xyz + (size_t)b * N * 3;
    for (int n = gid; n < N; n += stride) {
        const float* p = base + (size_t)n * 3;
        #pragma unroll
        for (int k = 0; k < 3; k++) {
            float v = p[k];
            mn[k] = fminf(mn[k], v);
            mx[k] = fmaxf(mx[k], v);
        }
    }
    for (int o = 32; o > 0; o >>= 1) {
        #pragma unroll
        for (int k = 0; k < 3; k++) {
            mn[k] = fminf(mn[k], __shfl_xor(mn[k], o));
            mx[k] = fmaxf(mx[k], __shfl_xor(mx[k], o));
        }
    }
    __shared__ float smn[4][3], smx[4][3];
    int w = tid >> 6;
    if ((tid & 63) == 0) {
        #pragma unroll
        for (int k = 0; k < 3; k++) { smn[w][k] = mn[k]; smx[w][k] = mx[k]; }
    }
    __syncthreads();
    if (tid == 0) {
        #pragma unroll
        for (int k = 0; k < 3; k++) {
            float a = fminf(fminf(smn[0][k], smn[1][k]), fminf(smn[2][k], smn[3][k]));
            float c = fmaxf(fmaxf(smx[0][k], smx[1][k]), fmaxf(smx[2][k], smx[3][k]));
            atomicMin(&mm[b * 6 + k], enc_f(a));
            atomicMax(&mm[b * 6 + 3 + k], enc_f(c));
        }
    }
}

__global__ void k_idx(const float* __restrict__ xyz,
                      const unsigned int* __restrict__ mm,
                      float* __restrict__ out_idx,
                      int* __restrict__ idx_i,
                      int* __restrict__ cnt, int N) {
    int n = blockIdx.x * blockDim.x + threadIdx.x;
    int b = blockIdx.y;
    if (n >= N) return;
    const float CLIP_HI = 1.0f - 1e-6f;
    const float* p = xyz + ((size_t)b * N + n) * 3;
    int vi[3];
    #pragma unroll
    for (int k = 0; k < 3; k++) {
        float mnv = dec_f(mm[b * 6 + k]);
        float mxv = dec_f(mm[b * 6 + 3 + k]);
        float rng = (mxv - mnv) + 1e-8f;
        float t = (p[k] - mnv) / rng;
        t = fminf(fmaxf(t, 0.0f), CLIP_HI);
        int q = (int)floorf(t * 32.0f);
        q = min(max(q, 0), GG - 1);
        vi[k] = q;
    }
    int idx = vi[0] * (GG * GG) + vi[1] * GG + vi[2];
    out_idx[(size_t)b * N + n] = (float)idx;
    idx_i[(size_t)b * N + n] = idx;
    atomicAdd(&cnt[b * NV + idx], 1);
}

// One block of 1024 threads per batch; exclusive scan of cnt[b][0..NV).
__global__ void k_scan(const int* __restrict__ cnt,
                       int* __restrict__ offs, int* __restrict__ curs) {
    __shared__ int part[1024];
    int b = blockIdx.x, t = threadIdx.x;
    const int PER = NV / 1024;          // 32
    int base = b * NV + t * PER;
    int loc[PER];
    int s = 0;
    #pragma unroll
    for (int i = 0; i < PER; i++) { loc[i] = cnt[base + i]; s += loc[i]; }
    part[t] = s;
    __syncthreads();
    for (int o = 1; o < 1024; o <<= 1) {
        int v = (t >= o) ? part[t - o] : 0;
        __syncthreads();
        part[t] += v;
        __syncthreads();
    }
    int ex = part[t] - s;
    #pragma unroll
    for (int i = 0; i < PER; i++) {
        offs[base + i] = ex;
        curs[base + i] = ex;
        ex += loc[i];
    }
}

// rank[n] = final position of point n in voxel-sorted order (within batch).
__global__ void k_rank(const int* __restrict__ idx_i,
                       int* __restrict__ curs,
                       int* __restrict__ rank, int N) {
    int n = blockIdx.x * blockDim.x + threadIdx.x;
    int b = blockIdx.y;
    if (n >= N) return;
    int idx = idx_i[(size_t)b * N + n];
    rank[(size_t)b * N + n] = atomicAdd(&curs[b * NV + idx], 1);
}

// [D,N] -> voxel-sorted [N,D] tiled transpose: row for point n lands at
// featT[rank[n]*DD + d]. Each 32-wide row chunk is a 128B-aligned full-line
// write (rank*512 + d0*128), so scattering costs no write amplification.
__global__ void k_transpose(const float* __restrict__ feat,
                            float* __restrict__ featT,
                            const int* __restrict__ rank, int N,
                            int b_base, size_t fstride) {
    __shared__ float tile[32][33];
    __shared__ int rk[32];
    int b = b_base + blockIdx.z;
    float* ft = featT + (size_t)blockIdx.z * fstride;
    int n0 = blockIdx.x * 32;
    int d0 = blockIdx.y * 32;
    int tid = threadIdx.x;
    int tx = tid & 31, ty = tid >> 5;   // ty in 0..7
    const float* fb = feat + (size_t)b * DD * N;
    if (ty == 0) {
        int nn = n0 + tx;
        rk[tx] = (nn < N) ? rank[(size_t)b * N + nn] : 0;
    }
    #pragma unroll
    for (int r = 0; r < 4; r++) {
        int dl = ty + r * 8;
        int nn = n0 + tx;
        if (nn < N) tile[dl][tx] = fb[(size_t)(d0 + dl) * N + nn];
    }
    __syncthreads();
    #pragma unroll
    for (int r = 0; r < 4; r++) {
        int nl = ty + r * 8;
        int nn = n0 + nl;
        if (nn < N) ft[(size_t)rk[nl] * DD + d0 + tx] = tile[tx][nl];
    }
}

// Block = 128 threads (one per d), VPB=32 consecutive voxels per block.
// featT is voxel-sorted, so the block streams a contiguous run of point rows
// (sequential addresses, no indirection). Per-voxel maxes live in a statically
// indexed register tile m[VPB]; epilogue writes 8 float4 per thread = 128 B
// contiguous per lane -> full-line stores (kills the 10x write amplification
// of the old one-dword-per-line pattern).
__global__ void k_reduce(const float* __restrict__ featT,
                         const int* __restrict__ offs,
                         float* __restrict__ out, int N,
                         int b_base, size_t fstride) {
    int b = b_base + blockIdx.z;
    const float* ft = featT + (size_t)blockIdx.z * fstride;
    int v0 = blockIdx.x * VPB;
    int d = threadIdx.x;                 // 0..127
    __shared__ int bnd[VPB + 1];
    if (d <= VPB) {
        int v = v0 + d;
        bnd[d] = (v < NV) ? offs[b * NV + v] : N;
    }
    __syncthreads();
    float m[VPB];
    int i = bnd[0];
    #pragma unroll
    for (int j = 0; j < VPB; j++) {
        int e = bnd[j + 1];
        float mv = (i < e) ? -INFINITY : 0.0f;   // empty voxel -> 0
        for (; i < e; i++) mv = fmaxf(mv, ft[(size_t)i * DD + d]);
        m[j] = mv;
    }
    float4* op = (float4*)(out + ((size_t)b * DD + d) * NV + v0);
    #pragma unroll
    for (int j = 0; j < VPB / 4; j++) {
        op[j] = make_float4(m[4 * j], m[4 * j + 1], m[4 * j + 2], m[4 * j + 3]);
    }
}

__global__ void k_fin_tail(float* __restrict__ out,
                           const unsigned int* __restrict__ mm,
                           long off_cnt, long off_mm) {
    int i = blockIdx.x * blockDim.x + threadIdx.x;
    if (i < BB * NV) {
        int c = ((const int*)out)[off_cnt + i];
        out[off_cnt + i] = (float)c;
    }
    if (i < BB * 3) {
        int b = i / 3, k = i % 3;
        out[off_mm + i]      = dec_f(mm[b * 6 + k]);
        out[off_mm + 12 + i] = dec_f(mm[b * 6 + 3 + k]);
    }
}

// ---- legacy fallback (tiny ws): atomics directly into out [B,D,V] ----

__global__ void k_init_legacy(unsigned int* __restrict__ out_u, long nvox,
                              unsigned int* __restrict__ mm,
                              unsigned int* __restrict__ cnt, long ncnt) {
    long i = blockIdx.x * (long)blockDim.x + threadIdx.x;
    long stride = gridDim.x * (long)blockDim.x;
    for (long j = i; j < nvox; j += stride) out_u[j] = ENC_NEG_INF;
    for (long j = i; j < ncnt; j += stride) cnt[j] = 0u;
    if (i < BB * 6) mm[i] = ((i % 6) < 3) ? ENC_POS_INF : ENC_NEG_INF;
}

__global__ void k_scatter_legacy(const float* __restrict__ feat,
                                 const float* __restrict__ out_idx,
                                 unsigned int* __restrict__ vox, int N) {
    int n = blockIdx.x * blockDim.x + threadIdx.x;
    int b = blockIdx.y;
    if (n >= N) return;
    int idx = (int)out_idx[(size_t)b * N + n];
    const float* fp = feat + (size_t)b * DD * N + n;
    unsigned int* vp = vox + (size_t)b * DD * NV + idx;
    #pragma unroll 4
    for (int d = 0; d < DD; d++) {
        atomicMax(vp + (size_t)d * NV, enc_f(fp[(size_t)d * N]));
    }
}

__global__ void k_fin_vox_legacy(unsigned int* __restrict__ out_u,
                                 const int* __restrict__ cnt) {
    size_t i = blockIdx.x * (size_t)blockDim.x + threadIdx.x;
    int b = (int)(i >> 22);
    int v = (int)(i & (NV - 1));
    unsigned int u = out_u[i];
    float f = (cnt[b * NV + v] == 0) ? 0.0f : dec_f(u);
    ((float*)out_u)[i] = f;
}

extern "C" void kernel_launch(void* const* d_in, const int* in_sizes, int n_in,
                              void* d_out, int out_size, void* d_ws, size_t ws_size,
                              hipStream_t stream) {
    const float* features = (const float*)d_in[0];   // [B, D, N]
    const float* xyz      = (const float*)d_in[1];   // [B, N, 3]
    int N = in_sizes[1] / (BB * 3);                  // 100000

    float* out = (float*)d_out;
    unsigned int* ws_u = (unsigned int*)d_ws;

    const long nvox    = (long)BB * DD * NV;
    const long off_idx = nvox;
    const long off_cnt = off_idx + (long)BB * N;
    const long ncnt    = (long)BB * NV;
    const long off_mm  = off_cnt + ncnt;

    float* out_idx = out + off_idx;
    int*   cnt     = (int*)(out + off_cnt);

    int nb = (N + 255) / 256;

    // ws extras (after featT region): idx_i [B*N], offs [B*NV], curs [B*NV],
    // rank [B*N], mm [24]
    const long extras = (long)BB * N * 2 + (long)BB * NV * 2 + 24;
    const long featT_small = (long)N * DD;           // one batch
    const long featT_big   = (long)BB * N * DD;      // all batches

    bool big   = ws_size >= (size_t)(featT_big + extras) * 4;
    bool small = ws_size >= (size_t)(featT_small + extras) * 4;

    if (small || big) {
        long ftw = big ? featT_big : featT_small;
        float* featT  = (float*)ws_u;
        int*   idx_i  = (int*)ws_u + ftw;
        int*   offs   = idx_i + (long)BB * N;
        int*   curs   = offs + (long)BB * NV;
        int*   rank   = curs + (long)BB * NV;
        unsigned int* mm = (unsigned int*)(rank + (long)BB * N);

        k_init_small<<<(BB * NV + 255) / 256, 256, 0, stream>>>(cnt, mm);
        k_minmax<<<dim3(64, BB), 256, 0, stream>>>(xyz, mm, N);
        k_idx<<<dim3(nb, BB), 256, 0, stream>>>(xyz, mm, out_idx, idx_i, cnt, N);
        k_scan<<<BB, 1024, 0, stream>>>(cnt, offs, curs);
        k_rank<<<dim3(nb, BB), 256, 0, stream>>>(idx_i, curs, rank, N);
        if (big) {
            size_t fstride = (size_t)N * DD;
            k_transpose<<<dim3((N + 31) / 32, DD / 32, BB), 256, 0, stream>>>(
                features, featT, rank, N, 0, fstride);
            k_reduce<<<dim3(NV / VPB, 1, BB), DD, 0, stream>>>(
                featT, offs, out, N, 0, fstride);
        } else {
            for (int b = 0; b < BB; b++) {
                k_transpose<<<dim3((N + 31) / 32, DD / 32, 1), 256, 0, stream>>>(
                    features, featT, rank, N, b, 0);
                k_reduce<<<dim3(NV / VPB, 1, 1), DD, 0, stream>>>(
                    featT, offs, out, N, b, 0);
            }
        }
        k_fin_tail<<<(int)((ncnt + 255) / 256), 256, 0, stream>>>(out, mm, off_cnt, off_mm);
    } else {
        unsigned int* mm = ws_u;
        k_init_legacy<<<2048, 256, 0, stream>>>((unsigned int*)out, nvox, mm,
                                                (unsigned int*)cnt, ncnt);
        k_minmax<<<dim3(64, BB), 256, 0, stream>>>(xyz, mm, N);
        k_idx<<<dim3(nb, BB), 256, 0, stream>>>(xyz, mm, out_idx,
                                                (int*)(out + off_idx), cnt, N);
        k_scatter_legacy<<<dim3(nb, BB), 256, 0, stream>>>(features, out_idx,
                                                           (unsigned int*)out, N);
        k_fin_vox_legacy<<<(unsigned)(nvox / 256), 256, 0, stream>>>(
            (unsigned int*)out, cnt);
        k_fin_tail<<<(int)((ncnt + 255) / 256), 256, 0, stream>>>(out, mm, off_cnt, off_mm);
    }
}

// Round 3
// 344.346 us; speedup vs baseline: 1.8196x; 1.3683x over previous
//
#include <hip/hip_runtime.h>
#include <math.h>

#define GG 32
#define NV (GG * GG * GG)      // 32768 voxels
#define BB 4
#define DD 128

// Monotone order-preserving float->uint encoding.
__device__ __forceinline__ unsigned int enc_f(float f) {
    unsigned int u = __float_as_uint(f);
    return (u & 0x80000000u) ? ~u : (u | 0x80000000u);
}
__device__ __forceinline__ float dec_f(unsigned int u) {
    return __uint_as_float((u & 0x80000000u) ? (u ^ 0x80000000u) : ~u);
}
#define ENC_NEG_INF 0x007FFFFFu
#define ENC_POS_INF 0xFF800000u

__global__ void k_init_small(int* __restrict__ cnt, unsigned int* __restrict__ mm) {
    int i = blockIdx.x * blockDim.x + threadIdx.x;
    if (i < BB * NV) cnt[i] = 0;
    if (i < BB * 6) mm[i] = ((i % 6) < 3) ? ENC_POS_INF : ENC_NEG_INF;
}

// grid (64, BB), block 256. Per-thread grid-stride accumulate, wave butterfly,
// LDS cross-wave, ONE thread per block does the 6 atomics (contention fix).
__global__ void k_minmax(const float* __restrict__ xyz,
                         unsigned int* __restrict__ mm, int N) {
    int b = blockIdx.y;
    int tid = threadIdx.x;
    int gid = blockIdx.x * blockDim.x + tid;
    int stride = gridDim.x * blockDim.x;
    float mn[3] = {INFINITY, INFINITY, INFINITY};
    float mx[3] = {-INFINITY, -INFINITY, -INFINITY};
    const float* base = xyz + (size_t)b * N * 3;
    for (int n = gid; n < N; n += stride) {
        const float* p = base + (size_t)n * 3;
        #pragma unroll
        for (int k = 0; k < 3; k++) {
            float v = p[k];
            mn[k] = fminf(mn[k], v);
            mx[k] = fmaxf(mx[k], v);
        }
    }
    for (int o = 32; o > 0; o >>= 1) {
        #pragma unroll
        for (int k = 0; k < 3; k++) {
            mn[k] = fminf(mn[k], __shfl_xor(mn[k], o));
            mx[k] = fmaxf(mx[k], __shfl_xor(mx[k], o));
        }
    }
    __shared__ float smn[4][3], smx[4][3];
    int w = tid >> 6;
    if ((tid & 63) == 0) {
        #pragma unroll
        for (int k = 0; k < 3; k++) { smn[w][k] = mn[k]; smx[w][k] = mx[k]; }
    }
    __syncthreads();
    if (tid == 0) {
        #pragma unroll
        for (int k = 0; k < 3; k++) {
            float a = fminf(fminf(smn[0][k], smn[1][k]), fminf(smn[2][k], smn[3][k]));
            float c = fmaxf(fmaxf(smx[0][k], smx[1][k]), fmaxf(smx[2][k], smx[3][k]));
            atomicMin(&mm[b * 6 + k], enc_f(a));
            atomicMax(&mm[b * 6 + 3 + k], enc_f(c));
        }
    }
}

__global__ void k_idx(const float* __restrict__ xyz,
                      const unsigned int* __restrict__ mm,
                      float* __restrict__ out_idx,
                      int* __restrict__ idx_i,
                      int* __restrict__ cnt, int N) {
    int n = blockIdx.x * blockDim.x + threadIdx.x;
    int b = blockIdx.y;
    if (n >= N) return;
    const float CLIP_HI = 1.0f - 1e-6f;
    const float* p = xyz + ((size_t)b * N + n) * 3;
    int vi[3];
    #pragma unroll
    for (int k = 0; k < 3; k++) {
        float mnv = dec_f(mm[b * 6 + k]);
        float mxv = dec_f(mm[b * 6 + 3 + k]);
        float rng = (mxv - mnv) + 1e-8f;
        float t = (p[k] - mnv) / rng;
        t = fminf(fmaxf(t, 0.0f), CLIP_HI);
        int q = (int)floorf(t * 32.0f);
        q = min(max(q, 0), GG - 1);
        vi[k] = q;
    }
    int idx = vi[0] * (GG * GG) + vi[1] * GG + vi[2];
    out_idx[(size_t)b * N + n] = (float)idx;
    if (idx_i) idx_i[(size_t)b * N + n] = idx;
    atomicAdd(&cnt[b * NV + idx], 1);
}

// Fused scatter-max: one block per (d, b); the FULL voxel grid (32768 u32 =
// 128 KB) lives in this block's LDS (160 KB/CU on gfx950 -> 1 block/CU).
// Streams feat[b][d][:] (contiguous float4) + idx[b][:] (contiguous int4,
// L2-resident across the 128 d-blocks of a batch), LDS-atomicMax on encoded
// floats, then writes the out row coalesced as float4. Replaces the old
// transpose(410MB) + reduce(272MB) + scan + rank with ~280MB of HBM traffic.
__global__ void k_fuse(const float* __restrict__ feat,
                       const int* __restrict__ idx_i,
                       float* __restrict__ out, int N) {
    __shared__ unsigned int s[NV];
    int d = blockIdx.x;
    int b = blockIdx.y;
    int t = threadIdx.x;                       // 0..1023
    const int T = 1024;
    for (int v = t; v < NV; v += T) s[v] = ENC_NEG_INF;
    __syncthreads();

    const float* fp = feat + ((size_t)b * DD + d) * N;
    const int*   ip = idx_i + (size_t)b * N;

    if ((N & 3) == 0) {
        const float4* f4 = (const float4*)fp;
        const int4*   i4 = (const int4*)ip;
        int n4 = N >> 2;
        for (int i = t; i < n4; i += T) {
            float4 f = f4[i];
            int4   x = i4[i];
            atomicMax(&s[x.x], enc_f(f.x));
            atomicMax(&s[x.y], enc_f(f.y));
            atomicMax(&s[x.z], enc_f(f.z));
            atomicMax(&s[x.w], enc_f(f.w));
        }
    } else {
        for (int i = t; i < N; i += T) atomicMax(&s[ip[i]], enc_f(fp[i]));
    }
    __syncthreads();

    float4* op = (float4*)(out + ((size_t)b * DD + d) * NV);
    for (int v = t; v < NV / 4; v += T) {
        unsigned int u0 = s[4 * v + 0];
        unsigned int u1 = s[4 * v + 1];
        unsigned int u2 = s[4 * v + 2];
        unsigned int u3 = s[4 * v + 3];
        float4 o;
        o.x = (u0 == ENC_NEG_INF) ? 0.0f : dec_f(u0);
        o.y = (u1 == ENC_NEG_INF) ? 0.0f : dec_f(u1);
        o.z = (u2 == ENC_NEG_INF) ? 0.0f : dec_f(u2);
        o.w = (u3 == ENC_NEG_INF) ? 0.0f : dec_f(u3);
        op[v] = o;
    }
}

__global__ void k_fin_tail(float* __restrict__ out,
                           const unsigned int* __restrict__ mm,
                           long off_cnt, long off_mm) {
    int i = blockIdx.x * blockDim.x + threadIdx.x;
    if (i < BB * NV) {
        int c = ((const int*)out)[off_cnt + i];
        out[off_cnt + i] = (float)c;
    }
    if (i < BB * 3) {
        int b = i / 3, k = i % 3;
        out[off_mm + i]      = dec_f(mm[b * 6 + k]);
        out[off_mm + 12 + i] = dec_f(mm[b * 6 + 3 + k]);
    }
}

// ---- legacy fallback (tiny ws): atomics directly into out [B,D,V] ----

__global__ void k_init_legacy(unsigned int* __restrict__ out_u, long nvox,
                              unsigned int* __restrict__ mm,
                              unsigned int* __restrict__ cnt, long ncnt) {
    long i = blockIdx.x * (long)blockDim.x + threadIdx.x;
    long stride = gridDim.x * (long)blockDim.x;
    for (long j = i; j < nvox; j += stride) out_u[j] = ENC_NEG_INF;
    for (long j = i; j < ncnt; j += stride) cnt[j] = 0u;
    if (i < BB * 6) mm[i] = ((i % 6) < 3) ? ENC_POS_INF : ENC_NEG_INF;
}

__global__ void k_scatter_legacy(const float* __restrict__ feat,
                                 const float* __restrict__ out_idx,
                                 unsigned int* __restrict__ vox, int N) {
    int n = blockIdx.x * blockDim.x + threadIdx.x;
    int b = blockIdx.y;
    if (n >= N) return;
    int idx = (int)out_idx[(size_t)b * N + n];
    const float* fp = feat + (size_t)b * DD * N + n;
    unsigned int* vp = vox + (size_t)b * DD * NV + idx;
    #pragma unroll 4
    for (int d = 0; d < DD; d++) {
        atomicMax(vp + (size_t)d * NV, enc_f(fp[(size_t)d * N]));
    }
}

__global__ void k_fin_vox_legacy(unsigned int* __restrict__ out_u,
                                 const int* __restrict__ cnt) {
    size_t i = blockIdx.x * (size_t)blockDim.x + threadIdx.x;
    int b = (int)(i >> 22);
    int v = (int)(i & (NV - 1));
    unsigned int u = out_u[i];
    float f = (cnt[b * NV + v] == 0) ? 0.0f : dec_f(u);
    ((float*)out_u)[i] = f;
}

extern "C" void kernel_launch(void* const* d_in, const int* in_sizes, int n_in,
                              void* d_out, int out_size, void* d_ws, size_t ws_size,
                              hipStream_t stream) {
    const float* features = (const float*)d_in[0];   // [B, D, N]
    const float* xyz      = (const float*)d_in[1];   // [B, N, 3]
    int N = in_sizes[1] / (BB * 3);                  // 100000

    float* out = (float*)d_out;
    unsigned int* ws_u = (unsigned int*)d_ws;

    const long nvox    = (long)BB * DD * NV;
    const long off_idx = nvox;
    const long off_cnt = off_idx + (long)BB * N;
    const long ncnt    = (long)BB * NV;
    const long off_mm  = off_cnt + ncnt;

    float* out_idx = out + off_idx;
    int*   cnt     = (int*)(out + off_cnt);

    int nb = (N + 255) / 256;

    // fused path ws needs: idx_i [B*N] + mm [24]
    bool fused = ws_size >= (size_t)((long)BB * N + 24) * 4;

    if (fused) {
        int* idx_i = (int*)ws_u;
        unsigned int* mm = (unsigned int*)(idx_i + (long)BB * N);

        k_init_small<<<(BB * NV + 255) / 256, 256, 0, stream>>>(cnt, mm);
        k_minmax<<<dim3(64, BB), 256, 0, stream>>>(xyz, mm, N);
        k_idx<<<dim3(nb, BB), 256, 0, stream>>>(xyz, mm, out_idx, idx_i, cnt, N);
        k_fuse<<<dim3(DD, BB), 1024, 0, stream>>>(features, idx_i, out, N);
        k_fin_tail<<<(int)((ncnt + 255) / 256), 256, 0, stream>>>(out, mm, off_cnt, off_mm);
    } else {
        unsigned int* mm = ws_u;
        k_init_legacy<<<2048, 256, 0, stream>>>((unsigned int*)out, nvox, mm,
                                                (unsigned int*)cnt, ncnt);
        k_minmax<<<dim3(64, BB), 256, 0, stream>>>(xyz, mm, N);
        k_idx<<<dim3(nb, BB), 256, 0, stream>>>(xyz, mm, out_idx,
                                                (int*)NULL, cnt, N);
        k_scatter_legacy<<<dim3(nb, BB), 256, 0, stream>>>(features, out_idx,
                                                           (unsigned int*)out, N);
        k_fin_vox_legacy<<<(unsigned)(nvox / 256), 256, 0, stream>>>(
            (unsigned int*)out, cnt);
        k_fin_tail<<<(int)((ncnt + 255) / 256), 256, 0, stream>>>(out, mm, off_cnt, off_mm);
    }
}